// Round 10
// baseline (227.583 us; speedup 1.0000x reference)
//
#include <hip/hip_runtime.h>
#include <stdint.h>

#define S_LEN 2048
#define BATCH 2
#define DM 1024
#define NH 16
#define DH 64
#define MROWS 4096  // BATCH * S_LEN

typedef unsigned short u16;
typedef unsigned int u32;
typedef __attribute__((ext_vector_type(8))) short bf16x8;
typedef __attribute__((ext_vector_type(4))) float f32x4;
typedef __attribute__((ext_vector_type(2))) unsigned u32x2;

union pack8 { u32 w[4]; bf16x8 v8; };

__device__ inline u16 f2bf(float f) {
  union { float f; unsigned u; } v; v.f = f;
  unsigned u = v.u;
  unsigned r = u + 0x7fffu + ((u >> 16) & 1u);
  return (u16)(r >> 16);
}

__device__ inline u32 pkbf(float lo, float hi) {
  u32 r;
  asm("v_cvt_pk_bf16_f32 %0, %1, %2" : "=v"(r) : "v"(lo), "v"(hi));
  return r;
}

__device__ inline float bf2f(short s) {
  union { u32 u; float f; } c; c.u = ((u32)(u16)s) << 16;
  return c.f;
}

// ---------------- fp32 -> bf16 conversion for x, Wq, Wk, Wv, Wo ----------------
__global__ void convert_k(const float* __restrict__ x, const float* __restrict__ wq,
                          const float* __restrict__ wk, const float* __restrict__ wv,
                          const float* __restrict__ wo, u16* __restrict__ xb,
                          u16* __restrict__ wb) {
  int i = blockIdx.x * blockDim.x + threadIdx.x;
  const int total = (MROWS * DM + 4 * DM * DM) / 4;  // 2,097,152 float4 groups
  if (i >= total) return;
  int e = i * 4;
  const float* src;
  u16* dst;
  if (e < MROWS * DM) {
    src = x + e; dst = xb + e;
  } else {
    int j = e - MROWS * DM;
    int w = j >> 20;
    int o = j & ((1 << 20) - 1);
    src = (w == 0) ? wq + o : (w == 1) ? wk + o : (w == 2) ? wv + o : wo + o;
    dst = wb + j;
  }
  float4 v = *(const float4*)src;
  uint2 r;
  r.x = (unsigned)f2bf(v.x) | ((unsigned)f2bf(v.y) << 16);
  r.y = (unsigned)f2bf(v.z) | ((unsigned)f2bf(v.w) << 16);
  *(uint2*)dst = r;
}

// ---------------- RoPE cos/sin table [S][32]; also zero kmax[32] ----------------
__global__ void rope_k(float2* __restrict__ tab, float* __restrict__ kmax) {
  int i = blockIdx.x * blockDim.x + threadIdx.x;
  if (i < 32) kmax[i] = 0.f;
  if (i >= S_LEN * 32) return;
  int s = i >> 5, p = i & 31;
  float inv = expf(-(float)p * 0.28782313662425575f);  // ln(10000)/32
  float a = (float)s * inv;
  tab[i] = make_float2(cosf(a), sinf(a));
}

// ---------------- per-bh max row norm of K (for static softmax bound) ----------------
__global__ void knorm_k(const u16* __restrict__ K, float* __restrict__ kmax) {
  const int row = blockIdx.x * 256 + threadIdx.x;  // 65536 rows = B*H*S
  const int bh = row >> 11;
  const u16* p = K + (size_t)row * DH;
  float ss = 0.f;
#pragma unroll
  for (int i = 0; i < 8; i++) {
    bf16x8 v = *(const bf16x8*)(p + i * 8);
#pragma unroll
    for (int j = 0; j < 8; j++) { float f = bf2f(v[j]); ss += f * f; }
  }
  float kn = sqrtf(ss);
#pragma unroll
  for (int d = 1; d < 64; d <<= 1) kn = fmaxf(kn, __shfl_xor(kn, d));
  if ((threadIdx.x & 63) == 0)
    atomicMax((unsigned*)(kmax + bh), __float_as_uint(kn));
}

// ---------------- GEMM: C = A @ W^T + bias, fused epilogues ----------------
// mode 0: Q  -> rope, *0.125*log2e, bf16 [B,H,S,Dh]   (log2e folded so attn uses exp2)
// mode 1: K  -> rope, bf16 [B,H,S,Dh]
// mode 2: V  -> bf16 [B,H,Dh,S] with per-32 s-block permutation matching the
//               attn PV fragment (pos = ((j&15)>>2)*8 + (j>>4)*4 + (j&3))
// mode 3: O  -> fp32 [M, DM]
__launch_bounds__(256)
__global__ void gemm_k(const u16* __restrict__ A,
                       const u16* __restrict__ w0, const u16* __restrict__ w1,
                       const u16* __restrict__ w2,
                       const float* __restrict__ b0, const float* __restrict__ b1,
                       const float* __restrict__ b2,
                       const float2* __restrict__ rope,
                       void* __restrict__ o0, void* __restrict__ o1, void* __restrict__ o2,
                       int mode0) {
  const int mode = mode0 + (int)(blockIdx.x >> 8);
  const int tile = blockIdx.x & 255;
  const int mt = tile >> 3, nt = tile & 7;
  const int mbase = mt * 128, nbase = nt * 128;
  const u16* W = (mode == 1) ? w1 : (mode == 2) ? w2 : w0;
  const float* bias = (mode == 1) ? b1 : (mode == 2) ? b2 : b0;
  void* outp = (mode == 1) ? o1 : (mode == 2) ? o2 : o0;

  __shared__ u16 As[128 * 40];  // padded row stride 40 (2-way bank aliasing = free)
  __shared__ u16 Bs[128 * 40];

  const int t = threadIdx.x;
  const int lane = t & 63, wvi = t >> 6;
  const int lr = lane & 15, lg = lane >> 4;
  const int wm = (wvi >> 1) * 64, wn = (wvi & 1) * 64;

  f32x4 acc[4][4] = {};
  const int srow = t >> 2;        // 0..63
  const int scol = (t & 3) * 8;   // 0,8,16,24

  for (int kk = 0; kk < DM; kk += 32) {
    bf16x8 a0 = *(const bf16x8*)(A + (size_t)(mbase + srow) * DM + kk + scol);
    bf16x8 a1 = *(const bf16x8*)(A + (size_t)(mbase + 64 + srow) * DM + kk + scol);
    bf16x8 g0 = *(const bf16x8*)(W + (size_t)(nbase + srow) * DM + kk + scol);
    bf16x8 g1 = *(const bf16x8*)(W + (size_t)(nbase + 64 + srow) * DM + kk + scol);
    __syncthreads();
    *(bf16x8*)&As[srow * 40 + scol] = a0;
    *(bf16x8*)&As[(64 + srow) * 40 + scol] = a1;
    *(bf16x8*)&Bs[srow * 40 + scol] = g0;
    *(bf16x8*)&Bs[(64 + srow) * 40 + scol] = g1;
    __syncthreads();
    bf16x8 af[4], bfr[4];
#pragma unroll
    for (int mi = 0; mi < 4; mi++)
      af[mi] = *(const bf16x8*)&As[(wm + mi * 16 + lr) * 40 + lg * 8];
#pragma unroll
    for (int ni = 0; ni < 4; ni++)
      bfr[ni] = *(const bf16x8*)&Bs[(wn + ni * 16 + lr) * 40 + lg * 8];
#pragma unroll
    for (int mi = 0; mi < 4; mi++)
#pragma unroll
      for (int ni = 0; ni < 4; ni++)
        acc[mi][ni] = __builtin_amdgcn_mfma_f32_16x16x32_bf16(af[mi], bfr[ni], acc[mi][ni], 0, 0, 0);
  }

#pragma unroll
  for (int ni = 0; ni < 4; ni++) {
    const int col = nbase + wn + ni * 16 + lr;
    const float bv = bias[col];
#pragma unroll
    for (int mi = 0; mi < 4; mi++) {
      const int row0 = mbase + wm + mi * 16 + lg * 4;
      f32x4 v = acc[mi][ni];
#pragma unroll
      for (int r = 0; r < 4; r++) {
        float val = v[r] + bv;
        const int row = row0 + r;
        if (mode <= 1) {
          float nb = __shfl_xor(val, 1);
          const int d = col & 63, p = d >> 1, s = row & (S_LEN - 1);
          float2 cs = rope[s * 32 + p];
          float ov = (d & 1) ? (nb * cs.y + val * cs.x) : (val * cs.x - nb * cs.y);
          if (mode == 0) ov *= 0.18033688011112042f;  // 1/sqrt(Dh) * log2(e)
          const int b = row >> 11, h = col >> 6;
          ((u16*)outp)[((size_t)(b * NH + h) * S_LEN + s) * DH + d] = f2bf(ov);
        } else if (mode == 2) {
          const int b = row >> 11, h = col >> 6, d = col & 63, s = row & (S_LEN - 1);
          const int j = s & 31;
          const int pos = (s & ~31) + (((j & 15) >> 2) << 3) + ((j >> 4) << 2) + (j & 3);
          ((u16*)outp)[((size_t)(b * NH + h) * DH + d) * S_LEN + pos] = f2bf(val);
        } else {
          ((float*)outp)[(size_t)row * DM + col] = val;
        }
      }
    }
  }
}

// ---- static-bound softmax + PV for one chain (contiguous o[4]) ----
__device__ __forceinline__ void sm_pv(const float a[8], float m, float& l,
                                      bf16x8 v0, bf16x8 v1, bf16x8 v2, bf16x8 v3,
                                      f32x4* o) {
  float p[8];
#pragma unroll
  for (int r = 0; r < 8; r++) p[r] = __builtin_amdgcn_exp2f(a[r] - m);
  l += ((p[0] + p[1]) + (p[2] + p[3])) + ((p[4] + p[5]) + (p[6] + p[7]));
  pack8 pu;
  pu.w[0] = pkbf(p[0], p[1]);
  pu.w[1] = pkbf(p[2], p[3]);
  pu.w[2] = pkbf(p[4], p[5]);
  pu.w[3] = pkbf(p[6], p[7]);
  o[0] = __builtin_amdgcn_mfma_f32_16x16x32_bf16(v0, pu.v8, o[0], 0, 0, 0);
  o[1] = __builtin_amdgcn_mfma_f32_16x16x32_bf16(v1, pu.v8, o[1], 0, 0, 0);
  o[2] = __builtin_amdgcn_mfma_f32_16x16x32_bf16(v2, pu.v8, o[2], 0, 0, 0);
  o[3] = __builtin_amdgcn_mfma_f32_16x16x32_bf16(v3, pu.v8, o[3], 0, 0, 0);
}

// ---------------- causal flash attention: dual-chain kv-split IN ONE WAVE ----------------
// QBLK=16: wave owns q rows [qbase, qbase+16). Two independent kv-chains run
// interleaved in one branch-free joint loop: chain0 = steps [0,half), chain1 =
// [half,nst) incl. the masked diagonal. Both chains share the SAME static bound m
// (Cauchy-Schwarz), so the final merge is a pure IN-REGISTER sum (o0+o1, l0+l1):
// no LDS, no __syncthreads, no cross-wave anything. 4096 waves -> ~4/SIMD.
__launch_bounds__(64)
__global__ void attn_k(const u16* __restrict__ Q, const u16* __restrict__ K,
                       const u16* __restrict__ Vt, u16* __restrict__ Oo,
                       const float* __restrict__ kmax) {
  const int bh = blockIdx.x & 31;
  const int tile = blockIdx.x >> 5;         // 0..127
  const int qbase = tile * 16;
  const int lane = threadIdx.x;
  const int lr = lane & 15, lg = lane >> 4;

  const size_t qoff = ((size_t)bh * S_LEN + qbase + lr) * DH + lg * 8;
  const bf16x8 q0 = *(const bf16x8*)(Q + qoff);
  const bf16x8 q1 = *(const bf16x8*)(Q + qoff + 32);

  // ---- static softmax bound (prologue) ----
  float ss = 0.f;
#pragma unroll
  for (int j = 0; j < 8; j++) {
    float a0 = bf2f(q0[j]), a1 = bf2f(q1[j]);
    ss += a0 * a0 + a1 * a1;
  }
  ss += __shfl_xor(ss, 16); ss += __shfl_xor(ss, 32);
  const float m = sqrtf(ss) * kmax[bh];

  f32x4 o0[4] = {}, o1[4] = {};
  float l0 = 0.f, l1 = 0.f;
  const f32x4 zero = {};
  const int nst = (qbase + 47) >> 5;        // 32-wide kv steps; last one masked
  const int half = nst >> 1;                // chain0: [0,half)  chain1: [half,nst)
  const int jn = (nst - 1) >> 1;            // joint iterations (both chains)
  const int solo = half - jn;               // 0 or 1 extra chain0 step

  const u16* Kp0 = K + ((size_t)bh * S_LEN + lr) * DH + lg * 8;
  const u16* Kp1 = K + ((size_t)bh * S_LEN + half * 32 + lr) * DH + lg * 8;
  const u16* Vp0 = Vt + ((size_t)bh * DH + lr) * S_LEN + lg * 8;
  const u16* Vp1 = Vp0 + half * 32;

  bf16x8 kc00 = *(const bf16x8*)(Kp0);
  bf16x8 kc01 = *(const bf16x8*)(Kp0 + 32);
  bf16x8 kc02 = *(const bf16x8*)(Kp0 + 16 * DH);
  bf16x8 kc03 = *(const bf16x8*)(Kp0 + 16 * DH + 32);
  bf16x8 kc10 = *(const bf16x8*)(Kp1);
  bf16x8 kc11 = *(const bf16x8*)(Kp1 + 32);
  bf16x8 kc12 = *(const bf16x8*)(Kp1 + 16 * DH);
  bf16x8 kc13 = *(const bf16x8*)(Kp1 + 16 * DH + 32);

  // ---- joint hot loop: both chains, branch-free single BB ----
  for (int it = 0; it < jn; ++it) {
    bf16x8 va0 = *(const bf16x8*)(Vp0);
    bf16x8 va1 = *(const bf16x8*)(Vp0 + 16 * S_LEN);
    bf16x8 va2 = *(const bf16x8*)(Vp0 + 32 * S_LEN);
    bf16x8 va3 = *(const bf16x8*)(Vp0 + 48 * S_LEN);
    bf16x8 vb0 = *(const bf16x8*)(Vp1);
    bf16x8 vb1 = *(const bf16x8*)(Vp1 + 16 * S_LEN);
    bf16x8 vb2 = *(const bf16x8*)(Vp1 + 32 * S_LEN);
    bf16x8 vb3 = *(const bf16x8*)(Vp1 + 48 * S_LEN);
    Vp0 += 32; Vp1 += 32;

    f32x4 sa0 = __builtin_amdgcn_mfma_f32_16x16x32_bf16(kc00, q0, zero, 0, 0, 0);
    sa0 = __builtin_amdgcn_mfma_f32_16x16x32_bf16(kc01, q1, sa0, 0, 0, 0);
    f32x4 sa1 = __builtin_amdgcn_mfma_f32_16x16x32_bf16(kc02, q0, zero, 0, 0, 0);
    sa1 = __builtin_amdgcn_mfma_f32_16x16x32_bf16(kc03, q1, sa1, 0, 0, 0);
    f32x4 sb0 = __builtin_amdgcn_mfma_f32_16x16x32_bf16(kc10, q0, zero, 0, 0, 0);
    sb0 = __builtin_amdgcn_mfma_f32_16x16x32_bf16(kc11, q1, sb0, 0, 0, 0);
    f32x4 sb1 = __builtin_amdgcn_mfma_f32_16x16x32_bf16(kc12, q0, zero, 0, 0, 0);
    sb1 = __builtin_amdgcn_mfma_f32_16x16x32_bf16(kc13, q1, sb1, 0, 0, 0);

    // prefetch next step's K for both chains (chain1's last prefetch = masked step)
    Kp0 += 32 * DH;
    kc00 = *(const bf16x8*)(Kp0);
    kc01 = *(const bf16x8*)(Kp0 + 32);
    kc02 = *(const bf16x8*)(Kp0 + 16 * DH);
    kc03 = *(const bf16x8*)(Kp0 + 16 * DH + 32);
    Kp1 += 32 * DH;
    kc10 = *(const bf16x8*)(Kp1);
    kc11 = *(const bf16x8*)(Kp1 + 32);
    kc12 = *(const bf16x8*)(Kp1 + 16 * DH);
    kc13 = *(const bf16x8*)(Kp1 + 16 * DH + 32);

    float aa[8], ab[8];
#pragma unroll
    for (int r = 0; r < 4; r++) {
      aa[r] = sa0[r]; aa[4 + r] = sa1[r];
      ab[r] = sb0[r]; ab[4 + r] = sb1[r];
    }
    sm_pv(aa, m, l0, va0, va1, va2, va3, o0);
    sm_pv(ab, m, l1, vb0, vb1, vb2, vb3, o1);
  }

  // ---- optional solo chain0 step (nst even): kc0 holds step jn = half-1 ----
  if (solo) {
    bf16x8 va0 = *(const bf16x8*)(Vp0);
    bf16x8 va1 = *(const bf16x8*)(Vp0 + 16 * S_LEN);
    bf16x8 va2 = *(const bf16x8*)(Vp0 + 32 * S_LEN);
    bf16x8 va3 = *(const bf16x8*)(Vp0 + 48 * S_LEN);

    f32x4 sa0 = __builtin_amdgcn_mfma_f32_16x16x32_bf16(kc00, q0, zero, 0, 0, 0);
    sa0 = __builtin_amdgcn_mfma_f32_16x16x32_bf16(kc01, q1, sa0, 0, 0, 0);
    f32x4 sa1 = __builtin_amdgcn_mfma_f32_16x16x32_bf16(kc02, q0, zero, 0, 0, 0);
    sa1 = __builtin_amdgcn_mfma_f32_16x16x32_bf16(kc03, q1, sa1, 0, 0, 0);

    float aa[8];
#pragma unroll
    for (int r = 0; r < 4; r++) { aa[r] = sa0[r]; aa[4 + r] = sa1[r]; }
    sm_pv(aa, m, l0, va0, va1, va2, va3, o0);
  }

  // ---- chain1 masked diagonal step: kc1 holds step nst-1 (both parities) ----
  {
    bf16x8 vb0 = *(const bf16x8*)(Vp1);
    bf16x8 vb1 = *(const bf16x8*)(Vp1 + 16 * S_LEN);
    bf16x8 vb2 = *(const bf16x8*)(Vp1 + 32 * S_LEN);
    bf16x8 vb3 = *(const bf16x8*)(Vp1 + 48 * S_LEN);

    f32x4 sb0 = __builtin_amdgcn_mfma_f32_16x16x32_bf16(kc10, q0, zero, 0, 0, 0);
    sb0 = __builtin_amdgcn_mfma_f32_16x16x32_bf16(kc11, q1, sb0, 0, 0, 0);
    f32x4 sb1 = __builtin_amdgcn_mfma_f32_16x16x32_bf16(kc12, q0, zero, 0, 0, 0);
    sb1 = __builtin_amdgcn_mfma_f32_16x16x32_bf16(kc13, q1, sb1, 0, 0, 0);

    // valid iff kv row (nst-1)*32 + lg*4 + r (+16) <= q row qbase + lr
    const int qrel = qbase + lr - (nst - 1) * 32 - lg * 4;
    float ab[8];
#pragma unroll
    for (int r = 0; r < 4; r++) {
      ab[r]     = (r <= qrel)      ? sb0[r] : -__builtin_inff();
      ab[4 + r] = (r + 16 <= qrel) ? sb1[r] : -__builtin_inff();
    }
    sm_pv(ab, m, l1, vb0, vb1, vb2, vb3, o1);
  }

  // ---- in-register merge (same m in both chains) + epilogue ----
  float l = l0 + l1;
  l += __shfl_xor(l, 16); l += __shfl_xor(l, 32);
  const float rl = __builtin_amdgcn_rcpf(l);

  const int b = bh >> 4, h = bh & 15;
  const size_t obase = ((size_t)b * S_LEN + qbase + lr) * DM + h * DH;
#pragma unroll
  for (int dt = 0; dt < 4; dt++) {
    u32x2 pk;
    pk.x = pkbf((o0[dt][0] + o1[dt][0]) * rl, (o0[dt][1] + o1[dt][1]) * rl);
    pk.y = pkbf((o0[dt][2] + o1[dt][2]) * rl, (o0[dt][3] + o1[dt][3]) * rl);
    *(u32x2*)(Oo + obase + dt * 16 + lg * 4) = pk;
  }
}

// ---------------- host launcher ----------------
extern "C" void kernel_launch(void* const* d_in, const int* in_sizes, int n_in,
                              void* d_out, int out_size, void* d_ws, size_t ws_size,
                              hipStream_t stream) {
  const float* x  = (const float*)d_in[0];
  const float* Wq = (const float*)d_in[1];
  const float* bq = (const float*)d_in[2];
  const float* Wk = (const float*)d_in[3];
  const float* bk = (const float*)d_in[4];
  const float* Wv = (const float*)d_in[5];
  const float* bv = (const float*)d_in[6];
  const float* Wo = (const float*)d_in[7];
  const float* bo = (const float*)d_in[8];

  char* ws = (char*)d_ws;
  u16* xb    = (u16*)(ws);                 // 8 MB  [4096,1024] bf16
  u16* wb    = (u16*)(ws + (8u << 20));    // 8 MB  Wq,Wk,Wv,Wo bf16
  u16* Qb    = (u16*)(ws + (16u << 20));   // 8 MB  [B,H,S,Dh]
  u16* Kb    = (u16*)(ws + (24u << 20));   // 8 MB  [B,H,S,Dh]
  u16* Vtb   = (u16*)(ws + (32u << 20));   // 8 MB  [B,H,Dh,S] (s-permuted)
  u16* AOb   = (u16*)(ws + (40u << 20));   // 8 MB  [B*S, DM]
  float2* rt = (float2*)(ws + (48u << 20));            // 512 KB rope table
  float* kmx = (float*)(ws + (48u << 20) + (512u << 10));  // 128 B kmax[32]

  convert_k<<<8192, 256, 0, stream>>>(x, Wq, Wk, Wv, Wo, xb, wb);
  rope_k<<<256, 256, 0, stream>>>(rt, kmx);
  gemm_k<<<768, 256, 0, stream>>>(xb, wb, wb + (1u << 20), wb + (2u << 20),
                                  bq, bk, bv, rt, Qb, Kb, Vtb, 0);
  knorm_k<<<256, 256, 0, stream>>>(Kb, kmx);
  attn_k<<<4096, 64, 0, stream>>>(Qb, Kb, Vtb, AOb, kmx);
  gemm_k<<<256, 256, 0, stream>>>(AOb, wb + (3u << 20), wb + (3u << 20), wb + (3u << 20),
                                  bo, bo, bo, rt, d_out, d_out, d_out, 3);
}

// Round 11
// 171.319 us; speedup vs baseline: 1.3284x; 1.3284x over previous
//
#include <hip/hip_runtime.h>
#include <stdint.h>

#define S_LEN 2048
#define BATCH 2
#define DM 1024
#define NH 16
#define DH 64
#define MROWS 4096  // BATCH * S_LEN

typedef unsigned short u16;
typedef unsigned int u32;
typedef __attribute__((ext_vector_type(8))) short bf16x8;
typedef __attribute__((ext_vector_type(4))) float f32x4;
typedef __attribute__((ext_vector_type(2))) unsigned u32x2;

union pack8 { u32 w[4]; bf16x8 v8; };

__device__ inline u16 f2bf(float f) {
  union { float f; unsigned u; } v; v.f = f;
  unsigned u = v.u;
  unsigned r = u + 0x7fffu + ((u >> 16) & 1u);
  return (u16)(r >> 16);
}

__device__ inline u32 pkbf(float lo, float hi) {
  u32 r;
  asm("v_cvt_pk_bf16_f32 %0, %1, %2" : "=v"(r) : "v"(lo), "v"(hi));
  return r;
}

__device__ inline float bf2f(short s) {
  union { u32 u; float f; } c; c.u = ((u32)(u16)s) << 16;
  return c.f;
}

// ---------------- fp32 -> bf16 conversion for x, Wq, Wk, Wv, Wo ----------------
__global__ void convert_k(const float* __restrict__ x, const float* __restrict__ wq,
                          const float* __restrict__ wk, const float* __restrict__ wv,
                          const float* __restrict__ wo, u16* __restrict__ xb,
                          u16* __restrict__ wb) {
  int i = blockIdx.x * blockDim.x + threadIdx.x;
  const int total = (MROWS * DM + 4 * DM * DM) / 4;  // 2,097,152 float4 groups
  if (i >= total) return;
  int e = i * 4;
  const float* src;
  u16* dst;
  if (e < MROWS * DM) {
    src = x + e; dst = xb + e;
  } else {
    int j = e - MROWS * DM;
    int w = j >> 20;
    int o = j & ((1 << 20) - 1);
    src = (w == 0) ? wq + o : (w == 1) ? wk + o : (w == 2) ? wv + o : wo + o;
    dst = wb + j;
  }
  float4 v = *(const float4*)src;
  uint2 r;
  r.x = (unsigned)f2bf(v.x) | ((unsigned)f2bf(v.y) << 16);
  r.y = (unsigned)f2bf(v.z) | ((unsigned)f2bf(v.w) << 16);
  *(uint2*)dst = r;
}

// ---------------- RoPE cos/sin table [S][32]; also zero kmax[32] ----------------
__global__ void rope_k(float2* __restrict__ tab, float* __restrict__ kmax) {
  int i = blockIdx.x * blockDim.x + threadIdx.x;
  if (i < 32) kmax[i] = 0.f;
  if (i >= S_LEN * 32) return;
  int s = i >> 5, p = i & 31;
  float inv = expf(-(float)p * 0.28782313662425575f);  // ln(10000)/32
  float a = (float)s * inv;
  tab[i] = make_float2(cosf(a), sinf(a));
}

// ---------------- per-bh max row norm of K (for static softmax bound) ----------------
__global__ void knorm_k(const u16* __restrict__ K, float* __restrict__ kmax) {
  const int row = blockIdx.x * 256 + threadIdx.x;  // 65536 rows = B*H*S
  const int bh = row >> 11;
  const u16* p = K + (size_t)row * DH;
  float ss = 0.f;
#pragma unroll
  for (int i = 0; i < 8; i++) {
    bf16x8 v = *(const bf16x8*)(p + i * 8);
#pragma unroll
    for (int j = 0; j < 8; j++) { float f = bf2f(v[j]); ss += f * f; }
  }
  float kn = sqrtf(ss);
#pragma unroll
  for (int d = 1; d < 64; d <<= 1) kn = fmaxf(kn, __shfl_xor(kn, d));
  if ((threadIdx.x & 63) == 0)
    atomicMax((unsigned*)(kmax + bh), __float_as_uint(kn));
}

// ---------------- GEMM: C = A @ W^T + bias, fused epilogues ----------------
// mode 0: Q  -> rope, *0.125*log2e, bf16 [B,H,S,Dh]   (log2e folded so attn uses exp2)
// mode 1: K  -> rope, bf16 [B,H,S,Dh]
// mode 2: V  -> bf16 [B,H,Dh,S] with per-32 s-block permutation matching the
//               attn PV fragment (pos = ((j&15)>>2)*8 + (j>>4)*4 + (j&3))
// mode 3: O  -> fp32 [M, DM]
__launch_bounds__(256)
__global__ void gemm_k(const u16* __restrict__ A,
                       const u16* __restrict__ w0, const u16* __restrict__ w1,
                       const u16* __restrict__ w2,
                       const float* __restrict__ b0, const float* __restrict__ b1,
                       const float* __restrict__ b2,
                       const float2* __restrict__ rope,
                       void* __restrict__ o0, void* __restrict__ o1, void* __restrict__ o2,
                       int mode0) {
  const int mode = mode0 + (int)(blockIdx.x >> 8);
  const int tile = blockIdx.x & 255;
  const int mt = tile >> 3, nt = tile & 7;
  const int mbase = mt * 128, nbase = nt * 128;
  const u16* W = (mode == 1) ? w1 : (mode == 2) ? w2 : w0;
  const float* bias = (mode == 1) ? b1 : (mode == 2) ? b2 : b0;
  void* outp = (mode == 1) ? o1 : (mode == 2) ? o2 : o0;

  __shared__ u16 As[128 * 40];  // padded row stride 40 (2-way bank aliasing = free)
  __shared__ u16 Bs[128 * 40];

  const int t = threadIdx.x;
  const int lane = t & 63, wvi = t >> 6;
  const int lr = lane & 15, lg = lane >> 4;
  const int wm = (wvi >> 1) * 64, wn = (wvi & 1) * 64;

  f32x4 acc[4][4] = {};
  const int srow = t >> 2;        // 0..63
  const int scol = (t & 3) * 8;   // 0,8,16,24

  for (int kk = 0; kk < DM; kk += 32) {
    bf16x8 a0 = *(const bf16x8*)(A + (size_t)(mbase + srow) * DM + kk + scol);
    bf16x8 a1 = *(const bf16x8*)(A + (size_t)(mbase + 64 + srow) * DM + kk + scol);
    bf16x8 g0 = *(const bf16x8*)(W + (size_t)(nbase + srow) * DM + kk + scol);
    bf16x8 g1 = *(const bf16x8*)(W + (size_t)(nbase + 64 + srow) * DM + kk + scol);
    __syncthreads();
    *(bf16x8*)&As[srow * 40 + scol] = a0;
    *(bf16x8*)&As[(64 + srow) * 40 + scol] = a1;
    *(bf16x8*)&Bs[srow * 40 + scol] = g0;
    *(bf16x8*)&Bs[(64 + srow) * 40 + scol] = g1;
    __syncthreads();
    bf16x8 af[4], bfr[4];
#pragma unroll
    for (int mi = 0; mi < 4; mi++)
      af[mi] = *(const bf16x8*)&As[(wm + mi * 16 + lr) * 40 + lg * 8];
#pragma unroll
    for (int ni = 0; ni < 4; ni++)
      bfr[ni] = *(const bf16x8*)&Bs[(wn + ni * 16 + lr) * 40 + lg * 8];
#pragma unroll
    for (int mi = 0; mi < 4; mi++)
#pragma unroll
      for (int ni = 0; ni < 4; ni++)
        acc[mi][ni] = __builtin_amdgcn_mfma_f32_16x16x32_bf16(af[mi], bfr[ni], acc[mi][ni], 0, 0, 0);
  }

#pragma unroll
  for (int ni = 0; ni < 4; ni++) {
    const int col = nbase + wn + ni * 16 + lr;
    const float bv = bias[col];
#pragma unroll
    for (int mi = 0; mi < 4; mi++) {
      const int row0 = mbase + wm + mi * 16 + lg * 4;
      f32x4 v = acc[mi][ni];
#pragma unroll
      for (int r = 0; r < 4; r++) {
        float val = v[r] + bv;
        const int row = row0 + r;
        if (mode <= 1) {
          float nb = __shfl_xor(val, 1);
          const int d = col & 63, p = d >> 1, s = row & (S_LEN - 1);
          float2 cs = rope[s * 32 + p];
          float ov = (d & 1) ? (nb * cs.y + val * cs.x) : (val * cs.x - nb * cs.y);
          if (mode == 0) ov *= 0.18033688011112042f;  // 1/sqrt(Dh) * log2(e)
          const int b = row >> 11, h = col >> 6;
          ((u16*)outp)[((size_t)(b * NH + h) * S_LEN + s) * DH + d] = f2bf(ov);
        } else if (mode == 2) {
          const int b = row >> 11, h = col >> 6, d = col & 63, s = row & (S_LEN - 1);
          const int j = s & 31;
          const int pos = (s & ~31) + (((j & 15) >> 2) << 3) + ((j >> 4) << 2) + (j & 3);
          ((u16*)outp)[((size_t)(b * NH + h) * DH + d) * S_LEN + pos] = f2bf(val);
        } else {
          ((float*)outp)[(size_t)row * DM + col] = val;
        }
      }
    }
  }
}

// ---- static-bound softmax + PV for one (chain, q-group): accumulate into o[4] ----
__device__ __forceinline__ void sm_pv(const float a[8], float m, float& l,
                                      bf16x8 v0, bf16x8 v1, bf16x8 v2, bf16x8 v3,
                                      f32x4* o) {
  float p[8];
#pragma unroll
  for (int r = 0; r < 8; r++) p[r] = __builtin_amdgcn_exp2f(a[r] - m);
  l += ((p[0] + p[1]) + (p[2] + p[3])) + ((p[4] + p[5]) + (p[6] + p[7]));
  pack8 pu;
  pu.w[0] = pkbf(p[0], p[1]);
  pu.w[1] = pkbf(p[2], p[3]);
  pu.w[2] = pkbf(p[4], p[5]);
  pu.w[3] = pkbf(p[6], p[7]);
  o[0] = __builtin_amdgcn_mfma_f32_16x16x32_bf16(v0, pu.v8, o[0], 0, 0, 0);
  o[1] = __builtin_amdgcn_mfma_f32_16x16x32_bf16(v1, pu.v8, o[1], 0, 0, 0);
  o[2] = __builtin_amdgcn_mfma_f32_16x16x32_bf16(v2, pu.v8, o[2], 0, 0, 0);
  o[3] = __builtin_amdgcn_mfma_f32_16x16x32_bf16(v3, pu.v8, o[3], 0, 0, 0);
}

// ---------------- causal flash attention: QBLK=32 + in-wave dual-chain kv-split ----
// Composition of the two PROVEN structures: R7's QBLK=32 (two q-groups share
// every K/V fragment -> 8 loads : 32 MFMAs per joint iter) and R10's verified
// in-wave kv-split (chain0 = [0,half), chain1 = [half,nst) incl. masked diagonal;
// makespan halved). Same static Cauchy-Schwarz bound m for both chains -> both
// accumulate into the SAME o/l registers (PV is linear). No LDS, no barriers.
__launch_bounds__(64)
__global__ void attn_k(const u16* __restrict__ Q, const u16* __restrict__ K,
                       const u16* __restrict__ Vt, u16* __restrict__ Oo,
                       const float* __restrict__ kmax) {
  const int bh = blockIdx.x & 31;
  const int tile = 63 - (blockIdx.x >> 5);  // longest first (causal load balance)
  const int qbase = tile * 32;
  const int lane = threadIdx.x;
  const int lr = lane & 15, lg = lane >> 4;

  const size_t qoff = ((size_t)bh * S_LEN + qbase + lr) * DH + lg * 8;
  const bf16x8 qA0 = *(const bf16x8*)(Q + qoff);
  const bf16x8 qA1 = *(const bf16x8*)(Q + qoff + 32);
  const bf16x8 qB0 = *(const bf16x8*)(Q + qoff + 16 * DH);
  const bf16x8 qB1 = *(const bf16x8*)(Q + qoff + 16 * DH + 32);

  // ---- static softmax bounds (prologue, off the hot loop) ----
  float ssA = 0.f, ssB = 0.f;
#pragma unroll
  for (int j = 0; j < 8; j++) {
    float a0 = bf2f(qA0[j]), a1 = bf2f(qA1[j]);
    float b0 = bf2f(qB0[j]), b1 = bf2f(qB1[j]);
    ssA += a0 * a0 + a1 * a1;
    ssB += b0 * b0 + b1 * b1;
  }
  ssA += __shfl_xor(ssA, 16); ssA += __shfl_xor(ssA, 32);
  ssB += __shfl_xor(ssB, 16); ssB += __shfl_xor(ssB, 32);
  const float kmx = kmax[bh];
  const float mA = sqrtf(ssA) * kmx;
  const float mB = sqrtf(ssB) * kmx;

  f32x4 oA[4] = {}, oB[4] = {};
  float lA = 0.f, lB = 0.f;
  const f32x4 zero = {};
  const int nst = tile + 1;                 // 32-wide kv steps; last one masked
  const int half = nst >> 1;                // chain0: [0,half)  chain1: [half,nst)
  const int jn = (nst - 1) >> 1;            // joint iterations (both chains)
  const int solo = half - jn;               // 0 or 1 extra chain0 step

  const u16* Kp0 = K + ((size_t)bh * S_LEN + lr) * DH + lg * 8;
  const u16* Kp1 = K + ((size_t)bh * S_LEN + half * 32 + lr) * DH + lg * 8;
  const u16* Vp0 = Vt + ((size_t)bh * DH + lr) * S_LEN + lg * 8;
  const u16* Vp1 = Vp0 + half * 32;

  bf16x8 kc00 = *(const bf16x8*)(Kp0);
  bf16x8 kc01 = *(const bf16x8*)(Kp0 + 32);
  bf16x8 kc02 = *(const bf16x8*)(Kp0 + 16 * DH);
  bf16x8 kc03 = *(const bf16x8*)(Kp0 + 16 * DH + 32);
  bf16x8 kc10 = *(const bf16x8*)(Kp1);
  bf16x8 kc11 = *(const bf16x8*)(Kp1 + 32);
  bf16x8 kc12 = *(const bf16x8*)(Kp1 + 16 * DH);
  bf16x8 kc13 = *(const bf16x8*)(Kp1 + 16 * DH + 32);

  // ---- joint hot loop: both chains x both q-groups, branch-free single BB ----
  for (int it = 0; it < jn; ++it) {
    bf16x8 va0 = *(const bf16x8*)(Vp0);
    bf16x8 va1 = *(const bf16x8*)(Vp0 + 16 * S_LEN);
    bf16x8 va2 = *(const bf16x8*)(Vp0 + 32 * S_LEN);
    bf16x8 va3 = *(const bf16x8*)(Vp0 + 48 * S_LEN);
    bf16x8 vb0 = *(const bf16x8*)(Vp1);
    bf16x8 vb1 = *(const bf16x8*)(Vp1 + 16 * S_LEN);
    bf16x8 vb2 = *(const bf16x8*)(Vp1 + 32 * S_LEN);
    bf16x8 vb3 = *(const bf16x8*)(Vp1 + 48 * S_LEN);
    Vp0 += 32; Vp1 += 32;

    // chain0 scores (both q-groups share kc0*)
    f32x4 sa0A = __builtin_amdgcn_mfma_f32_16x16x32_bf16(kc00, qA0, zero, 0, 0, 0);
    sa0A = __builtin_amdgcn_mfma_f32_16x16x32_bf16(kc01, qA1, sa0A, 0, 0, 0);
    f32x4 sa1A = __builtin_amdgcn_mfma_f32_16x16x32_bf16(kc02, qA0, zero, 0, 0, 0);
    sa1A = __builtin_amdgcn_mfma_f32_16x16x32_bf16(kc03, qA1, sa1A, 0, 0, 0);
    f32x4 sa0B = __builtin_amdgcn_mfma_f32_16x16x32_bf16(kc00, qB0, zero, 0, 0, 0);
    sa0B = __builtin_amdgcn_mfma_f32_16x16x32_bf16(kc01, qB1, sa0B, 0, 0, 0);
    f32x4 sa1B = __builtin_amdgcn_mfma_f32_16x16x32_bf16(kc02, qB0, zero, 0, 0, 0);
    sa1B = __builtin_amdgcn_mfma_f32_16x16x32_bf16(kc03, qB1, sa1B, 0, 0, 0);
    // chain1 scores (share kc1*)
    f32x4 sb0A = __builtin_amdgcn_mfma_f32_16x16x32_bf16(kc10, qA0, zero, 0, 0, 0);
    sb0A = __builtin_amdgcn_mfma_f32_16x16x32_bf16(kc11, qA1, sb0A, 0, 0, 0);
    f32x4 sb1A = __builtin_amdgcn_mfma_f32_16x16x32_bf16(kc12, qA0, zero, 0, 0, 0);
    sb1A = __builtin_amdgcn_mfma_f32_16x16x32_bf16(kc13, qA1, sb1A, 0, 0, 0);
    f32x4 sb0B = __builtin_amdgcn_mfma_f32_16x16x32_bf16(kc10, qB0, zero, 0, 0, 0);
    sb0B = __builtin_amdgcn_mfma_f32_16x16x32_bf16(kc11, qB1, sb0B, 0, 0, 0);
    f32x4 sb1B = __builtin_amdgcn_mfma_f32_16x16x32_bf16(kc12, qB0, zero, 0, 0, 0);
    sb1B = __builtin_amdgcn_mfma_f32_16x16x32_bf16(kc13, qB1, sb1B, 0, 0, 0);

    // prefetch next step's K for both chains (chain1's last prefetch = masked step)
    Kp0 += 32 * DH;
    kc00 = *(const bf16x8*)(Kp0);
    kc01 = *(const bf16x8*)(Kp0 + 32);
    kc02 = *(const bf16x8*)(Kp0 + 16 * DH);
    kc03 = *(const bf16x8*)(Kp0 + 16 * DH + 32);
    Kp1 += 32 * DH;
    kc10 = *(const bf16x8*)(Kp1);
    kc11 = *(const bf16x8*)(Kp1 + 32);
    kc12 = *(const bf16x8*)(Kp1 + 16 * DH);
    kc13 = *(const bf16x8*)(Kp1 + 16 * DH + 32);

    float a0A[8], a0B[8], a1A[8], a1B[8];
#pragma unroll
    for (int r = 0; r < 4; r++) {
      a0A[r] = sa0A[r]; a0A[4 + r] = sa1A[r];
      a0B[r] = sa0B[r]; a0B[4 + r] = sa1B[r];
      a1A[r] = sb0A[r]; a1A[4 + r] = sb1A[r];
      a1B[r] = sb0B[r]; a1B[4 + r] = sb1B[r];
    }
    sm_pv(a0A, mA, lA, va0, va1, va2, va3, oA);
    sm_pv(a0B, mB, lB, va0, va1, va2, va3, oB);
    sm_pv(a1A, mA, lA, vb0, vb1, vb2, vb3, oA);
    sm_pv(a1B, mB, lB, vb0, vb1, vb2, vb3, oB);
  }

  // ---- optional solo chain0 step (nst even): kc0 holds step jn = half-1 ----
  if (solo) {
    bf16x8 va0 = *(const bf16x8*)(Vp0);
    bf16x8 va1 = *(const bf16x8*)(Vp0 + 16 * S_LEN);
    bf16x8 va2 = *(const bf16x8*)(Vp0 + 32 * S_LEN);
    bf16x8 va3 = *(const bf16x8*)(Vp0 + 48 * S_LEN);

    f32x4 s0A = __builtin_amdgcn_mfma_f32_16x16x32_bf16(kc00, qA0, zero, 0, 0, 0);
    s0A = __builtin_amdgcn_mfma_f32_16x16x32_bf16(kc01, qA1, s0A, 0, 0, 0);
    f32x4 s1A = __builtin_amdgcn_mfma_f32_16x16x32_bf16(kc02, qA0, zero, 0, 0, 0);
    s1A = __builtin_amdgcn_mfma_f32_16x16x32_bf16(kc03, qA1, s1A, 0, 0, 0);
    f32x4 s0B = __builtin_amdgcn_mfma_f32_16x16x32_bf16(kc00, qB0, zero, 0, 0, 0);
    s0B = __builtin_amdgcn_mfma_f32_16x16x32_bf16(kc01, qB1, s0B, 0, 0, 0);
    f32x4 s1B = __builtin_amdgcn_mfma_f32_16x16x32_bf16(kc02, qB0, zero, 0, 0, 0);
    s1B = __builtin_amdgcn_mfma_f32_16x16x32_bf16(kc03, qB1, s1B, 0, 0, 0);

    float aA[8], aB[8];
#pragma unroll
    for (int r = 0; r < 4; r++) {
      aA[r] = s0A[r]; aA[4 + r] = s1A[r];
      aB[r] = s0B[r]; aB[4 + r] = s1B[r];
    }
    sm_pv(aA, mA, lA, va0, va1, va2, va3, oA);
    sm_pv(aB, mB, lB, va0, va1, va2, va3, oB);
  }

  // ---- chain1 masked diagonal step: kc1 holds step nst-1 (both parities) ----
  {
    bf16x8 vb0 = *(const bf16x8*)(Vp1);
    bf16x8 vb1 = *(const bf16x8*)(Vp1 + 16 * S_LEN);
    bf16x8 vb2 = *(const bf16x8*)(Vp1 + 32 * S_LEN);
    bf16x8 vb3 = *(const bf16x8*)(Vp1 + 48 * S_LEN);

    f32x4 s0A = __builtin_amdgcn_mfma_f32_16x16x32_bf16(kc10, qA0, zero, 0, 0, 0);
    s0A = __builtin_amdgcn_mfma_f32_16x16x32_bf16(kc11, qA1, s0A, 0, 0, 0);
    f32x4 s1A = __builtin_amdgcn_mfma_f32_16x16x32_bf16(kc12, qA0, zero, 0, 0, 0);
    s1A = __builtin_amdgcn_mfma_f32_16x16x32_bf16(kc13, qA1, s1A, 0, 0, 0);
    f32x4 s0B = __builtin_amdgcn_mfma_f32_16x16x32_bf16(kc10, qB0, zero, 0, 0, 0);
    s0B = __builtin_amdgcn_mfma_f32_16x16x32_bf16(kc11, qB1, s0B, 0, 0, 0);
    f32x4 s1B = __builtin_amdgcn_mfma_f32_16x16x32_bf16(kc12, qB0, zero, 0, 0, 0);
    s1B = __builtin_amdgcn_mfma_f32_16x16x32_bf16(kc13, qB1, s1B, 0, 0, 0);

    // A group: q = qbase+lr; valid iff kv row qbase+lg*4+r (+16) <= q
    const int qrelA = lr - lg * 4;
    const int qrelB = qrelA + 16;
    float aA[8], aB[8];
#pragma unroll
    for (int r = 0; r < 4; r++) {
      aA[r]     = (r <= qrelA)      ? s0A[r] : -__builtin_inff();
      aA[4 + r] = (r + 16 <= qrelA) ? s1A[r] : -__builtin_inff();  // never valid
      aB[r]     = s0B[r];                                          // always valid
      aB[4 + r] = (r + 16 <= qrelB) ? s1B[r] : -__builtin_inff();
    }
    sm_pv(aA, mA, lA, vb0, vb1, vb2, vb3, oA);
    sm_pv(aB, mB, lB, vb0, vb1, vb2, vb3, oB);
  }

  // ---- epilogue: lane holds q=lr, d = dt*16 + lg*4 + r ----
  lA += __shfl_xor(lA, 16); lA += __shfl_xor(lA, 32);
  lB += __shfl_xor(lB, 16); lB += __shfl_xor(lB, 32);
  const float rlA = __builtin_amdgcn_rcpf(lA);
  const float rlB = __builtin_amdgcn_rcpf(lB);

  const int b = bh >> 4, h = bh & 15;
  const size_t obaseA = ((size_t)b * S_LEN + qbase + lr) * DM + h * DH;
  const size_t obaseB = obaseA + (size_t)16 * DM;
#pragma unroll
  for (int dt = 0; dt < 4; dt++) {
    u32x2 pkA, pkB;
    pkA.x = pkbf(oA[dt][0] * rlA, oA[dt][1] * rlA);
    pkA.y = pkbf(oA[dt][2] * rlA, oA[dt][3] * rlA);
    pkB.x = pkbf(oB[dt][0] * rlB, oB[dt][1] * rlB);
    pkB.y = pkbf(oB[dt][2] * rlB, oB[dt][3] * rlB);
    *(u32x2*)(Oo + obaseA + dt * 16 + lg * 4) = pkA;
    *(u32x2*)(Oo + obaseB + dt * 16 + lg * 4) = pkB;
  }
}

// ---------------- host launcher ----------------
extern "C" void kernel_launch(void* const* d_in, const int* in_sizes, int n_in,
                              void* d_out, int out_size, void* d_ws, size_t ws_size,
                              hipStream_t stream) {
  const float* x  = (const float*)d_in[0];
  const float* Wq = (const float*)d_in[1];
  const float* bq = (const float*)d_in[2];
  const float* Wk = (const float*)d_in[3];
  const float* bk = (const float*)d_in[4];
  const float* Wv = (const float*)d_in[5];
  const float* bv = (const float*)d_in[6];
  const float* Wo = (const float*)d_in[7];
  const float* bo = (const float*)d_in[8];

  char* ws = (char*)d_ws;
  u16* xb    = (u16*)(ws);                 // 8 MB  [4096,1024] bf16
  u16* wb    = (u16*)(ws + (8u << 20));    // 8 MB  Wq,Wk,Wv,Wo bf16
  u16* Qb    = (u16*)(ws + (16u << 20));   // 8 MB  [B,H,S,Dh]
  u16* Kb    = (u16*)(ws + (24u << 20));   // 8 MB  [B,H,S,Dh]
  u16* Vtb   = (u16*)(ws + (32u << 20));   // 8 MB  [B,H,Dh,S] (s-permuted)
  u16* AOb   = (u16*)(ws + (40u << 20));   // 8 MB  [B*S, DM]
  float2* rt = (float2*)(ws + (48u << 20));            // 512 KB rope table
  float* kmx = (float*)(ws + (48u << 20) + (512u << 10));  // 128 B kmax[32]

  convert_k<<<8192, 256, 0, stream>>>(x, Wq, Wk, Wv, Wo, xb, wb);
  rope_k<<<256, 256, 0, stream>>>(rt, kmx);
  gemm_k<<<768, 256, 0, stream>>>(xb, wb, wb + (1u << 20), wb + (2u << 20),
                                  bq, bk, bv, rt, Qb, Kb, Vtb, 0);
  knorm_k<<<256, 256, 0, stream>>>(Kb, kmx);
  attn_k<<<2048, 64, 0, stream>>>(Qb, Kb, Vtb, AOb, kmx);
  gemm_k<<<256, 256, 0, stream>>>(AOb, wb + (3u << 20), wb + (3u << 20), wb + (3u << 20),
                                  bo, bo, bo, rt, d_out, d_out, d_out, 3);
}